// Round 12
// baseline (568.627 us; speedup 1.0000x reference)
//
#include <hip/hip_runtime.h>
#include <math.h>

#define TSEQ   2048
#define DIMM   512
#define NHEAD  8
#define DHD    64
#define BHD    16      // BATCH*HEADS
#define NHASHK 4
#define CHUNKS 128     // NHASHK * (TSEQ/64)
#define FFD    2048
#define NROWS  4096    // BATCH*TSEQ

#define OFF_WQK 0
#define OFF_WV  262144
#define OFF_WO  524288
#define OFF_W1  786432
#define OFF_W2  1835008
#define WT_TOT  2883584

typedef unsigned short u16;
typedef _Float16 f16;
typedef __attribute__((ext_vector_type(8))) _Float16 f16x8;
typedef __attribute__((ext_vector_type(4))) float f32x4;
typedef __attribute__((ext_vector_type(8))) unsigned short ushort8v;
typedef __attribute__((ext_vector_type(4))) unsigned short ushort4v;

__device__ inline u16 h16(float f) {
  union { f16 h; u16 u; } x;
  x.h = (f16)f;
  return x.u;
}
__device__ inline float f16f(u16 u) {
  union { u16 u; f16 h; } x;
  x.u = u;
  return (float)x.h;
}
__device__ inline f16x8 mk8f(unsigned a, unsigned b, unsigned c, unsigned d) {
  union { unsigned u[4]; f16x8 v; } x;
  x.u[0] = a; x.u[1] = b; x.u[2] = c; x.u[3] = d;
  return x.v;
}
__device__ inline float gelu_exact(float v) {
  return 0.5f * v * (1.0f + erff(v * 0.70710678118654752f));
}
// XOR swizzle for 128-byte LDS rows: 16B slot index ^= (row&7) -> 2-way max (free)
__device__ inline int swz128(int row, int colbyte) {
  return row * 128 + (colbyte ^ ((row & 7) << 4));
}
// transposed V LDS: byte address of Vt[d][k] (u16), stride 264B + half offset
#define VT(d, k) ((d) * 264 + (((d) & 32) ? 8 : 0) + ((k) << 1))

// ---------------- embed ----------------
__global__ __launch_bounds__(128) void k_embed(const int* __restrict__ x, const float* __restrict__ emb,
                                               float* __restrict__ x1, float* __restrict__ x2) {
  int row = blockIdx.x;
  int tok = x[row];
  float4 v = ((const float4*)(emb + (size_t)tok * DIMM))[threadIdx.x];
  ((float4*)(x1 + (size_t)row * DIMM))[threadIdx.x] = v;
  ((float4*)(x2 + (size_t)row * DIMM))[threadIdx.x] = v;
}

// ---------------- sin/cos tables ----------------
__global__ __launch_bounds__(256) void k_sincos(float* __restrict__ sin_t, float* __restrict__ cos_t) {
  int idx = blockIdx.x * 256 + threadIdx.x;   // TSEQ*32
  int t = idx >> 5, i = idx & 31;
  float inv = powf(10000.0f, -(float)(2 * i) / 64.0f);
  float ang = (float)t * inv;
  sin_t[idx] = sinf(ang);
  cos_t[idx] = cosf(ang);
}

// ---------------- layernorm (row = 512) -> fp16 ----------------
__global__ __launch_bounds__(256) void k_layernorm(const float* __restrict__ x, const float* __restrict__ g,
                                                   const float* __restrict__ b, u16* __restrict__ dst) {
  int row = blockIdx.x, tid = threadIdx.x;
  const float* xr = x + (size_t)row * DIMM;
  float v0 = xr[tid], v1 = xr[tid + 256];
  int lane = tid & 63, w = tid >> 6;
  __shared__ float red[8];
  float s = v0 + v1;
#pragma unroll
  for (int o = 32; o; o >>= 1) s += __shfl_xor(s, o);
  if (lane == 0) red[w] = s;
  __syncthreads();
  float mu = (red[0] + red[1] + red[2] + red[3]) * (1.0f / DIMM);
  float d0 = v0 - mu, d1 = v1 - mu;
  float q = d0 * d0 + d1 * d1;
#pragma unroll
  for (int o = 32; o; o >>= 1) q += __shfl_xor(q, o);
  if (lane == 0) red[4 + w] = q;
  __syncthreads();
  float var = (red[4] + red[5] + red[6] + red[7]) * (1.0f / DIMM);
  float rstd = 1.0f / sqrtf(var + 1e-5f);
  size_t base = (size_t)row * DIMM;
  dst[base + tid] = h16(d0 * rstd * g[tid] + b[tid]);
  dst[base + tid + 256] = h16(d1 * rstd * g[tid + 256] + b[tid + 256]);
}

// ---------------- ALL-layer weight prep: transpose + fp16 (4 x 2820 blocks) ----------------
__global__ __launch_bounds__(256) void k_prep(const float* __restrict__ Wqk, const float* __restrict__ Wv,
                                              const float* __restrict__ Wo, const float* __restrict__ W1,
                                              const float* __restrict__ W2, const float* __restrict__ rot,
                                              u16* __restrict__ wt16, u16* __restrict__ rt16) {
  __shared__ float tile[32][33];
  const int L = blockIdx.x / 2820;
  const int idx = blockIdx.x - L * 2820;
  Wqk += (size_t)L * 262144;
  Wv  += (size_t)L * 262144;
  Wo  += (size_t)L * 262144;
  W1  += (size_t)L * 1048576;
  W2  += (size_t)L * 1048576;
  rot += (size_t)L * 4096;
  u16* wt = wt16 + (size_t)L * WT_TOT;
  u16* rt = rt16 + (size_t)L * 4096;
  const float* src;
  u16* dh;
  int K, N, k0, n0;
  if (idx < 768) {
    int w = idx >> 8, r = idx & 255;
    K = 512; N = 512; k0 = (r >> 4) << 5; n0 = (r & 15) << 5;
    src = (w == 0) ? Wqk : (w == 1) ? Wv : Wo;
    dh = wt + (size_t)w * 262144;
  } else if (idx < 1792) {
    int r = idx - 768;
    K = 512; N = 2048; k0 = (r >> 6) << 5; n0 = (r & 63) << 5;
    src = W1; dh = wt + OFF_W1;
  } else if (idx < 2816) {
    int r = idx - 1792;
    K = 2048; N = 512; k0 = (r >> 4) << 5; n0 = (r & 15) << 5;
    src = W2; dh = wt + OFF_W2;
  } else {
    int r = idx - 2816;
    K = 64; N = 64; k0 = (r >> 1) << 5; n0 = (r & 1) << 5;
    src = rot; dh = rt;
  }
  const int t = threadIdx.x;
  const int r = t >> 3, c4 = (t & 7) << 2;
  float4 v = *(const float4*)&src[(size_t)(k0 + r) * N + n0 + c4];
  tile[r][c4] = v.x; tile[r][c4 + 1] = v.y; tile[r][c4 + 2] = v.z; tile[r][c4 + 3] = v.w;
  __syncthreads();
  u16 hs[4];
#pragma unroll
  for (int i = 0; i < 4; ++i) hs[i] = h16(tile[c4 + i][r]);
  size_t o = (size_t)(n0 + r) * K + k0 + c4;
  *(ushort4v*)&dh[o] = (ushort4v){hs[0], hs[1], hs[2], hs[3]};
}

// ---------------- fp16 MFMA GEMM: C = A[M][K] * B^T (Bt[N][K]), BK=64, depth-2 prefetch ----------------
// STORE: 1 = out += val + bias (residual fp32); 4 = gelu(val+bias) -> fp16
//        5 = fused QKV (BN=64 only): gn<512 -> rotary -> qk16 + fused LSH bucket; gn>=512 -> v16
template <int BM, int BN, int STORE>
__global__ __launch_bounds__(256, 4) void k_gemm16(
    const u16* __restrict__ A, const u16* __restrict__ Bt,
    const float* __restrict__ bias, float* __restrict__ out,
    u16* __restrict__ out16, u16* __restrict__ qk16, u16* __restrict__ v16,
    int K, int N,
    const float* __restrict__ sin_t, const float* __restrict__ cos_t,
    const u16* __restrict__ rt16, int* __restrict__ bucket) {
  constexpr int MF = BM / 32;    // m-frags per wave
  constexpr int NF = BN / 32;    // n-frags per wave
  constexpr int ACH = BM / 32;   // A 16B-chunks per thread per K-step
  constexpr int BCH = BN / 32;   // B 16B-chunks per thread per K-step
  __shared__ __align__(16) char AsB[BM * 128];
  __shared__ __align__(16) char BsB[BN * 128];
  const int bm = blockIdx.x * BM, bn = blockIdx.y * BN;
  const int tid = threadIdx.x, lane = tid & 63, wid = tid >> 6;
  const int wm = (wid >> 1) * (BM / 2), wn = (wid & 1) * (BN / 2);
  const int l16 = lane & 15, g = lane >> 4;
  f32x4 acc[MF][NF];
#pragma unroll
  for (int m = 0; m < MF; ++m)
#pragma unroll
    for (int n = 0; n < NF; ++n) acc[m][n] = (f32x4){0.f, 0.f, 0.f, 0.f};

  const int srow = tid >> 3;            // 0..31
  const int scolb = (tid & 7) << 4;     // 16B chunk col within 128B row
  const u16* ap = A + (size_t)(bm + srow) * K + ((tid & 7) << 3);
  const u16* bp = Bt + (size_t)(bn + srow) * K + ((tid & 7) << 3);

  // two named in-flight register sets (depth-2 pipeline; no runtime indexing)
  ushort8v paA[ACH], pbA[BCH], paB[ACH], pbB[BCH];
#pragma unroll
  for (int i = 0; i < ACH; ++i) paA[i] = *(const ushort8v*)(ap + (size_t)(i << 5) * K);
#pragma unroll
  for (int i = 0; i < BCH; ++i) pbA[i] = *(const ushort8v*)(bp + (size_t)(i << 5) * K);
#pragma unroll
  for (int i = 0; i < ACH; ++i) paB[i] = *(const ushort8v*)(ap + (size_t)(i << 5) * K + 64);
#pragma unroll
  for (int i = 0; i < BCH; ++i) pbB[i] = *(const ushort8v*)(bp + (size_t)(i << 5) * K + 64);

  auto gstep = [&](ushort8v (&PA)[ACH], ushort8v (&PB)[BCH], int S) {
#pragma unroll
    for (int i = 0; i < ACH; ++i)
      *(ushort8v*)(AsB + swz128(srow + (i << 5), scolb)) = PA[i];
#pragma unroll
    for (int i = 0; i < BCH; ++i)
      *(ushort8v*)(BsB + swz128(srow + (i << 5), scolb)) = PB[i];
    __syncthreads();
    const int kf = (S + 2) << 6;
    if (kf < K) {   // issue loads for step S+2 (in flight across ~2 K-steps)
#pragma unroll
      for (int i = 0; i < ACH; ++i) PA[i] = *(const ushort8v*)(ap + (size_t)(i << 5) * K + kf);
#pragma unroll
      for (int i = 0; i < BCH; ++i) PB[i] = *(const ushort8v*)(bp + (size_t)(i << 5) * K + kf);
    }
#pragma unroll
    for (int ks = 0; ks < 2; ++ks) {
      f16x8 af[MF], bfr[NF];
#pragma unroll
      for (int m = 0; m < MF; ++m)
        af[m] = *(const f16x8*)(AsB + swz128(wm + (m << 4) + l16, ((ks << 2) + g) << 4));
#pragma unroll
      for (int n = 0; n < NF; ++n)
        bfr[n] = *(const f16x8*)(BsB + swz128(wn + (n << 4) + l16, ((ks << 2) + g) << 4));
#pragma unroll
      for (int m = 0; m < MF; ++m)
#pragma unroll
        for (int n = 0; n < NF; ++n)
          acc[m][n] = __builtin_amdgcn_mfma_f32_16x16x32_f16(af[m], bfr[n], acc[m][n], 0, 0, 0);
    }
    __syncthreads();
  };

  const int nsteps = K >> 6;            // always even (K = 512 or 2048)
  for (int s = 0; s < nsteps; s += 2) {
    gstep(paA, pbA, s);
    gstep(paB, pbB, s + 1);
  }

  // bucket path: preload rot^T (8KB) into regs early to hide latency
  const bool do_bucket = (STORE == 5) && (bn < 512);
  ushort8v prt0{}, prt1{};
  if (do_bucket) {
    int i0 = tid, i1 = tid + 256;               // 16B chunk ids, 512 total
    prt0 = *(const ushort8v*)(rt16 + (i0 >> 3) * 64 + ((i0 & 7) << 3));
    prt1 = *(const ushort8v*)(rt16 + (i1 >> 3) * 64 + ((i1 & 7) << 3));
  }

  // epilogue (C/D: col = lane&15 -> B rows, row = (lane>>4)*4 + reg -> A rows)
#pragma unroll
  for (int m = 0; m < MF; ++m) {
#pragma unroll
    for (int n = 0; n < NF; ++n) {
      const int gn = bn + wn + (n << 4) + l16;
      float bv = 0.f;
      if (STORE == 1 || STORE == 4) bv = bias[gn];
#pragma unroll
      for (int r = 0; r < 4; ++r) {
        const int gm = bm + wm + (m << 4) + (g << 2) + r;
        float val = acc[m][n][r];
        if (STORE == 1) {
          out[(size_t)gm * N + gn] += val + bv;
        } else if (STORE == 4) {
          out16[(size_t)gm * N + gn] = h16(gelu_exact(val + bv));
        } else {  // STORE == 5
          const float pv = __shfl_xor(val, 1);
          const int bb = gm >> 11, tt = gm & (TSEQ - 1);
          if (gn < 512) {
            const int hh = gn >> 6, dd = gn & 63;
            const int ip = dd >> 1;
            float cz = cos_t[tt * 32 + ip], sz = sin_t[tt * 32 + ip];
            float o = (dd & 1) ? (val * cz + pv * sz) : (val * cz - pv * sz);
            u16 oh = h16(o);
            qk16[((size_t)((bb * NHEAD + hh) * TSEQ + tt)) * DHD + dd] = oh;
            // stage rotated qk row into AsB for the fused bucket GEMM
            *(u16*)(AsB + swz128(gm - bm, dd << 1)) = oh;
          } else {
            const int gnn = gn - 512;
            const int hh = gnn >> 6, dd = gnn & 63;
            v16[((size_t)((bb * NHEAD + hh) * TSEQ + tt)) * DHD + dd] = h16(val);
          }
        }
      }
    }
  }

  if constexpr (STORE == 5) {
    if (do_bucket) {
      // write rot^T into BsB (swizzled), then mini-GEMM 64x64 @ 64x64 + argmax
      {
        int i0 = tid, i1 = tid + 256;
        *(ushort8v*)(BsB + swz128(i0 >> 3, (i0 & 7) << 4)) = prt0;
        *(ushort8v*)(BsB + swz128(i1 >> 3, (i1 & 7) << 4)) = prt1;
      }
      __syncthreads();
      const int bwm = (wid >> 1) << 5;    // token rows 0/32
      const int bwn = (wid & 1) << 5;     // hash cols 0/32
      f32x4 bacc[2][2];
#pragma unroll
      for (int m = 0; m < 2; ++m) { bacc[m][0] = (f32x4){0,0,0,0}; bacc[m][1] = (f32x4){0,0,0,0}; }
#pragma unroll
      for (int ks = 0; ks < 2; ++ks) {
        f16x8 bfr[2];
#pragma unroll
        for (int n = 0; n < 2; ++n)
          bfr[n] = *(const f16x8*)(BsB + swz128(bwn + (n << 4) + l16, (ks << 6) + (g << 4)));
#pragma unroll
        for (int m = 0; m < 2; ++m) {
          f16x8 afr = *(const f16x8*)(AsB + swz128(bwm + (m << 4) + l16, (ks << 6) + (g << 4)));
#pragma unroll
          for (int n = 0; n < 2; ++n)
            bacc[m][n] = __builtin_amdgcn_mfma_f32_16x16x32_f16(afr, bfr[n], bacc[m][n], 0, 0, 0);
        }
      }
      const int bb = bm >> 11;
      const int hh = bn >> 6;
#pragma unroll
      for (int m = 0; m < 2; ++m)
#pragma unroll
        for (int n = 0; n < 2; ++n) {
          const int hcol = (bwn >> 4) + n;
#pragma unroll
          for (int r = 0; r < 4; ++r) {
            float v = bacc[m][n][r];
            float best = v; int bi = l16;
            if (-v > best) { best = -v; bi = 16 + l16; }
#pragma unroll
            for (int o = 1; o < 16; o <<= 1) {
              float ob = __shfl_xor(best, o);
              int obi = __shfl_xor(bi, o);
              if (ob > best || (ob == best && obi < bi)) { best = ob; bi = obi; }
            }
            if (l16 == 0) {
              int t = (bm & (TSEQ - 1)) + bwm + (m << 4) + (g << 2) + r;
              bucket[((size_t)((bb * NHEAD + hh) * NHASHK) + hcol) * TSEQ + t] = bi;
            }
          }
        }
    }
  }
}

// ---------------- stable counting sort per (bh,h): 32 buckets, 2048 items ----------------
__global__ __launch_bounds__(256) void k_sort(const int* __restrict__ bucket, int* __restrict__ st) {
  __shared__ int hist[256][33];
  __shared__ int chunk[8][32];
  __shared__ int bbase[32];
  const int seg = blockIdx.x;
  const int tid = threadIdx.x;
  const int* bk = bucket + (size_t)seg * TSEQ;
  int4 u0 = *(const int4*)(bk + tid * 8);
  int4 u1 = *(const int4*)(bk + tid * 8 + 4);
  int myb[8] = {u0.x, u0.y, u0.z, u0.w, u1.x, u1.y, u1.z, u1.w};
#pragma unroll
  for (int j = 0; j < 33; ++j) hist[tid][j] = 0;
  __syncthreads();
#pragma unroll
  for (int i = 0; i < 8; ++i) hist[tid][myb[i]]++;
  __syncthreads();
  // two-level exclusive scan over producers (256) per bucket (32)
  const int b = tid & 31, c = tid >> 5;
  int ssum = 0;
  for (int g2 = c * 32; g2 < c * 32 + 32; ++g2) ssum += hist[g2][b];
  chunk[c][b] = ssum;
  __syncthreads();
  if (tid < 32) {
    int run = 0;
    for (int cc = 0; cc < 8; ++cc) { int v = chunk[cc][tid]; chunk[cc][tid] = run; run += v; }
    bbase[tid] = run;
  }
  __syncthreads();
  if (tid == 0) {
    int s = 0;
    for (int j = 0; j < 32; ++j) { int v = bbase[j]; bbase[j] = s; s += v; }
  }
  __syncthreads();
  int run = chunk[c][b];
  for (int g2 = c * 32; g2 < c * 32 + 32; ++g2) { int v = hist[g2][b]; hist[g2][b] = run; run += v; }
  __syncthreads();
  int* dst = st + (size_t)seg * TSEQ;
#pragma unroll
  for (int i = 0; i < 8; ++i) {
    int bb2 = myb[i];
    int p = bbase[bb2] + hist[tid][bb2];
    hist[tid][bb2]++;
    dst[p] = tid * 8 + i;
  }
}

// ---------------- chunked LSH attention (fp16 MFMA, K + transposed-V in LDS) ----------------
__global__ __launch_bounds__(256) void k_attn(const u16* __restrict__ qk16,
                                              const u16* __restrict__ v16,
                                              const int* __restrict__ st,
                                              u16* __restrict__ o4h, float* __restrict__ lg) {
  __shared__ __align__(16) char Kb[128 * 128];        // swizzled fp16 K rows
  __shared__ __align__(16) char Vb[64 * 264 + 16];    // transposed V: Vt[d][k]
  __shared__ float inv_norm[128];
  __shared__ int tids[128];
  __shared__ float pn[256];
  const int blk = blockIdx.x;
  const int c = blk & (CHUNKS - 1), bh = blk >> 7;
  const int h = c >> 5;
  const int tid = threadIdx.x, lane = tid & 63, wid = tid >> 6;
  const int l16 = lane & 15, g = lane >> 4;

  if (tid < 128) {
    int cc = (tid < 64) ? c : ((c + CHUNKS - 1) & (CHUNKS - 1));
    tids[tid] = st[bh * (NHASHK * TSEQ) + cc * 64 + (tid & 63)];
  }
  __syncthreads();
  {
    const int r = tid >> 1, hf = tid & 1;
    const u16* qsrc = qk16 + ((size_t)bh * TSEQ + tids[r]) * 64 + hf * 32;
    const u16* vsrc = v16 + ((size_t)bh * TSEQ + tids[r]) * 64 + hf * 32;
    float ss = 0.f;
#pragma unroll
    for (int i = 0; i < 4; ++i) {
      ushort8v u = *(const ushort8v*)(qsrc + i * 8);
      *(ushort8v*)(Kb + swz128(r, hf * 64 + i * 16)) = u;
#pragma unroll
      for (int j = 0; j < 8; ++j) { float f = f16f(u[j]); ss += f * f; }
      ushort8v vv8 = *(const ushort8v*)(vsrc + i * 8);
#pragma unroll
      for (int j = 0; j < 8; ++j)
        *(u16*)(Vb + VT(hf * 32 + i * 8 + j, r)) = vv8[j];
    }
    pn[tid] = ss;
  }
  __syncthreads();
  if (tid < 128) {
    float s2 = pn[2 * tid] + pn[2 * tid + 1];
    inv_norm[tid] = 1.0f / fmaxf(sqrtf(s2), 1e-12f);
  }
  __syncthreads();

  const int qrow = (wid << 4) + l16;
  const int tq = tids[qrow];
  const size_t obase = (size_t)(bh * NHASHK + h) * TSEQ + tq;

  // S^T = K_raw · Q^T : lane holds S[k][q] for its q-column
  f32x4 accs[8];
#pragma unroll
  for (int i = 0; i < 8; ++i) accs[i] = (f32x4){0, 0, 0, 0};
  __builtin_amdgcn_s_setprio(1);
#pragma unroll
  for (int s = 0; s < 2; ++s) {
    f16x8 qf = *(const f16x8*)(Kb + swz128(qrow, ((s << 2) + g) << 4));
#pragma unroll
    for (int mf = 0; mf < 8; ++mf) {
      f16x8 afr = *(const f16x8*)(Kb + swz128(mf * 16 + l16, ((s << 2) + g) << 4));
      accs[mf] = __builtin_amdgcn_mfma_f32_16x16x32_f16(afr, qf, accs[mf], 0, 0, 0);
    }
  }
  __builtin_amdgcn_s_setprio(0);
  float pv[8][4];
  float mx = -3e38f;
#pragma unroll
  for (int mf = 0; mf < 8; ++mf) {
    float4 invn = *(const float4*)&inv_norm[mf * 16 + g * 4];
    int4 tk = *(const int4*)&tids[mf * 16 + g * 4];
    float inva[4] = {invn.x, invn.y, invn.z, invn.w};
    int tka[4] = {tk.x, tk.y, tk.z, tk.w};
#pragma unroll
    for (int r = 0; r < 4; ++r) {
      float d = accs[mf][r] * inva[r] * 0.125f;
      if (tka[r] == tq) d = -5e4f;
      pv[mf][r] = d;
      mx = fmaxf(mx, d);
    }
  }
  mx = fmaxf(mx, __shfl_xor(mx, 16));
  mx = fmaxf(mx, __shfl_xor(mx, 32));
  float sum = 0.f;
#pragma unroll
  for (int mf = 0; mf < 8; ++mf)
#pragma unroll
    for (int r = 0; r < 4; ++r) {
      float e = __expf(pv[mf][r] - mx);
      pv[mf][r] = e;
      sum += e;
    }
  sum += __shfl_xor(sum, 16);
  sum += __shfl_xor(sum, 32);
  float lse = __logf(sum) + mx;
  float rs = 1.0f / sum;
  if (g == 0) lg[obase] = lse;
  // pack P pairs fp16: P2[mf][m] = (p_{2m}, p_{2m+1}) for k = 16mf + 4g + {2m,2m+1}
  unsigned P2[8][2];
#pragma unroll
  for (int mf = 0; mf < 8; ++mf)
#pragma unroll
    for (int m = 0; m < 2; ++m) {
      float p0 = pv[mf][2 * m] * rs, p1 = pv[mf][2 * m + 1] * rs;
      P2[mf][m] = (unsigned)h16(p0) | ((unsigned)h16(p1) << 16);
    }
  // PV: O^T = V^T · P^T  (A = V^T from transposed LDS, B = P via shfl redistribution)
  f32x4 acco[4];
#pragma unroll
  for (int i = 0; i < 4; ++i) acco[i] = (f32x4){0, 0, 0, 0};
#pragma unroll
  for (int s = 0; s < 4; ++s) {
    unsigned bw[4];
#pragma unroll
    for (int w = 0; w < 4; ++w) {
      int srl = l16 + (((2 * g + (w >> 1)) & 3) << 4);
      unsigned a0 = __shfl(P2[2 * s][w & 1], srl);
      unsigned a1 = __shfl(P2[2 * s + 1][w & 1], srl);
      bw[w] = (g >> 1) ? a1 : a0;
    }
    f16x8 pb = mk8f(bw[0], bw[1], bw[2], bw[3]);
    const int k0 = s * 32 + g * 8;
    __builtin_amdgcn_s_setprio(1);
#pragma unroll
    for (int mf = 0; mf < 4; ++mf) {
      const int dcol = mf * 16 + l16;
      uint2 v0 = *(const uint2*)(Vb + VT(dcol, k0));
      uint2 v1 = *(const uint2*)(Vb + VT(dcol, k0 + 4));
      f16x8 vf = mk8f(v0.x, v0.y, v1.x, v1.y);
      acco[mf] = __builtin_amdgcn_mfma_f32_16x16x32_f16(vf, pb, acco[mf], 0, 0, 0);
    }
    __builtin_amdgcn_s_setprio(0);
  }
#pragma unroll
  for (int mf = 0; mf < 4; ++mf) {
    ushort4v o4s = {h16(acco[mf][0]), h16(acco[mf][1]), h16(acco[mf][2]), h16(acco[mf][3])};
    *(ushort4v*)&o4h[obase * 64 + mf * 16 + g * 4] = o4s;
  }
}

// ---------------- combine hash rounds -> ctx fp16 [B,T,512] ----------------
__global__ __launch_bounds__(256) void k_combine(const u16* __restrict__ o4h, const float* __restrict__ lg,
                                                 u16* __restrict__ ctx16) {
  int tok = blockIdx.x * 4 + (threadIdx.x >> 6);   // over BHD*TSEQ
  int dd = threadIdx.x & 63;
  int bh = tok >> 11, t = tok & (TSEQ - 1);
  size_t base = (size_t)bh * NHASHK * TSEQ + t;
  float l0 = lg[base], l1 = lg[base + TSEQ], l2 = lg[base + 2 * TSEQ], l3 = lg[base + 3 * TSEQ];
  float m = fmaxf(fmaxf(l0, l1), fmaxf(l2, l3));
  float e0 = expf(l0 - m), e1 = expf(l1 - m), e2 = expf(l2 - m), e3 = expf(l3 - m);
  float inv = 1.0f / (e0 + e1 + e2 + e3);
  float o = (e0 * f16f(o4h[base * 64 + dd]) + e1 * f16f(o4h[(base + TSEQ) * 64 + dd]) +
             e2 * f16f(o4h[(base + 2 * TSEQ) * 64 + dd]) + e3 * f16f(o4h[(base + 3 * TSEQ) * 64 + dd])) * inv;
  int b = bh >> 3, hh = bh & 7;
  ctx16[((size_t)(b * TSEQ + t)) * DIMM + hh * DHD + dd] = h16(o);
}

// ---------------- fused final-LN + column-mean stage 1: 512 blocks x 8 rows ----------------
__global__ __launch_bounds__(256) void k_colmean1(const float* __restrict__ x1, const float* __restrict__ x2,
                                                  float* __restrict__ part) {
  const int blk = blockIdx.x;            // bb*256 + ch
  const int bb = blk >> 8, ch = blk & 255;
  const int tid = threadIdx.x, lane = tid & 63, w = tid >> 6;
  __shared__ float red[8];
  float a0 = 0.f, a1 = 0.f;
  for (int i = 0; i < 8; ++i) {
    int row = bb * TSEQ + ch * 8 + i;
    size_t base = (size_t)row * DIMM;
    float v0 = 0.5f * (x1[base + tid] + x2[base + tid]);
    float v1 = 0.5f * (x1[base + tid + 256] + x2[base + tid + 256]);
    float s = v0 + v1;
#pragma unroll
    for (int o = 32; o; o >>= 1) s += __shfl_xor(s, o);
    if (lane == 0) red[w] = s;
    __syncthreads();
    float mu = (red[0] + red[1] + red[2] + red[3]) * (1.0f / DIMM);
    float d0 = v0 - mu, d1 = v1 - mu;
    float q = d0 * d0 + d1 * d1;
#pragma unroll
    for (int o = 32; o; o >>= 1) q += __shfl_xor(q, o);
    if (lane == 0) red[4 + w] = q;
    __syncthreads();
    float var = (red[4] + red[5] + red[6] + red[7]) * (1.0f / DIMM);
    float rstd = 1.0f / sqrtf(var + 1e-5f);
    a0 += d0 * rstd;
    a1 += d1 * rstd;
    __syncthreads();
  }
  part[(size_t)blk * DIMM + tid] = a0;
  part[(size_t)blk * DIMM + tid + 256] = a1;
}

__global__ __launch_bounds__(256) void k_colmean2(const float* __restrict__ part,
                                                  const float* __restrict__ g, const float* __restrict__ b,
                                                  float* __restrict__ hm) {
  int gidx = blockIdx.x * 256 + threadIdx.x;   // 8192 = 1024 outputs x 8
  int oid = gidx >> 3, sub = gidx & 7;
  int bb = oid >> 9, d = oid & 511;
  float s = 0.f;
  for (int c = sub; c < 256; c += 8) s += part[((size_t)(bb * 256 + c)) * DIMM + d];
  s += __shfl_xor(s, 1);
  s += __shfl_xor(s, 2);
  s += __shfl_xor(s, 4);
  if (sub == 0) hm[oid] = s * (1.0f / TSEQ) * g[d] + b[d];
}

// ---------------- head (split-K head1 + reducing head2) ----------------
__global__ __launch_bounds__(256) void k_head1(const float* __restrict__ hm, const float* __restrict__ Wf1,
                                               float* __restrict__ r1p) {
  int b = blockIdx.x & 1, kc = blockIdx.x >> 1;   // 16 blocks: 2 batch x 8 k-chunks
  int j = threadIdx.x;
  float acc = 0;
  for (int k = kc * 64; k < kc * 64 + 64; ++k) acc += hm[b * DIMM + k] * Wf1[k * 256 + j];
  r1p[(size_t)(kc * 2 + b) * 256 + j] = acc;
}

__global__ __launch_bounds__(256) void k_head2(const float* __restrict__ r1p, const float* __restrict__ bf1,
                                               const float* __restrict__ Wout, const float* __restrict__ bout,
                                               float* __restrict__ outp) {
  int b = blockIdx.x;
  int tid = threadIdx.x, lane = tid & 63, w = tid >> 6;
  float s = 0.f;
#pragma unroll
  for (int kc = 0; kc < 8; ++kc) s += r1p[(size_t)(kc * 2 + b) * 256 + tid];
  float v = fmaxf(s + bf1[tid], 0.0f) * Wout[tid];
#pragma unroll
  for (int o = 32; o; o >>= 1) v += __shfl_xor(v, o);
  __shared__ float red[4];
  if (lane == 0) red[w] = v;
  __syncthreads();
  if (tid == 0) outp[b] = red[0] + red[1] + red[2] + red[3] + bout[0];
}

extern "C" void kernel_launch(void* const* d_in, const int* in_sizes, int n_in,
                              void* d_out, int out_size, void* d_ws, size_t ws_size,
                              hipStream_t stream) {
  const int*   x         = (const int*)d_in[0];
  const float* token_emb = (const float*)d_in[1];
  const float* ln1_s     = (const float*)d_in[2];
  const float* ln1_b     = (const float*)d_in[3];
  const float* Wqk       = (const float*)d_in[4];
  const float* Wv        = (const float*)d_in[5];
  const float* Wo        = (const float*)d_in[6];
  const float* bo        = (const float*)d_in[7];
  const float* ln2_s     = (const float*)d_in[8];
  const float* ln2_b     = (const float*)d_in[9];
  const float* W1        = (const float*)d_in[10];
  const float* b1        = (const float*)d_in[11];
  const float* W2        = (const float*)d_in[12];
  const float* b2        = (const float*)d_in[13];
  const float* rotations = (const float*)d_in[14];
  const float* lnf_s     = (const float*)d_in[15];
  const float* lnf_b     = (const float*)d_in[16];
  const float* Wf1       = (const float*)d_in[17];
  const float* bf1       = (const float*)d_in[18];
  const float* Wout      = (const float*)d_in[19];
  const float* bout      = (const float*)d_in[20];
  float* out = (float*)d_out;

  char* ws = (char*)d_ws;
  size_t off = 0;
  auto alloc = [&](size_t nbytes) {
    char* p = ws + off;
    off += (nbytes + 255) & ~(size_t)255;
    return p;
  };
  float*  x1     = (float*)alloc((size_t)NROWS * DIMM * 4);
  float*  x2     = (float*)alloc((size_t)NROWS * DIMM * 4);
  u16*    xn16   = (u16*)alloc((size_t)NROWS * DIMM * 2);
  u16*    qk16   = (u16*)alloc((size_t)BHD * TSEQ * DHD * 2);
  u16*    v16    = (u16*)alloc((size_t)BHD * TSEQ * DHD * 2);
  u16*    ffh16  = (u16*)alloc((size_t)NROWS * FFD * 2);
  u16*    o4h    = (u16*)alloc((size_t)BHD * NHASHK * TSEQ * DHD * 2);
  float*  lg     = (float*)alloc((size_t)BHD * NHASHK * TSEQ * 4);
  float*  sin_t  = (float*)alloc((size_t)TSEQ * 32 * 4);
  float*  cos_t  = (float*)alloc((size_t)TSEQ * 32 * 4);
  float*  part   = (float*)alloc((size_t)512 * DIMM * 4);
  float*  hm     = (float*)alloc(2 * DIMM * 4);
  float*  r1p    = (float*)alloc(16 * 256 * 4);
  int*    bucket = (int*)alloc((size_t)BHD * NHASHK * TSEQ * 4);
  int*    st     = (int*)alloc((size_t)BHD * NHASHK * TSEQ * 4);
  u16*    wt16   = (u16*)alloc((size_t)4 * WT_TOT * 2);
  u16*    rott16 = (u16*)alloc((size_t)4 * 64 * 64 * 2);
  u16*    ctx16  = xn16;   // alias: lifetimes disjoint

  k_embed<<<NROWS, 128, 0, stream>>>(x, token_emb, x1, x2);
  k_sincos<<<(TSEQ * 32) / 256, 256, 0, stream>>>(sin_t, cos_t);
  k_prep<<<4 * 2820, 256, 0, stream>>>(Wqk, Wv, Wo, W1, W2, rotations, wt16, rott16);

  for (int L = 0; L < 4; ++L) {
    u16* wt = wt16 + (size_t)L * WT_TOT;
    u16* rt = rott16 + (size_t)L * 4096;

    k_layernorm<<<NROWS, 256, 0, stream>>>(x2, ln1_s + L * DIMM, ln1_b + L * DIMM, xn16);
    // fused QK+V GEMM (+LSH bucket in qk-half epilogues): B = [Wqk^T ; Wv^T]
    k_gemm16<64, 64, 5><<<dim3(64, 16), 256, 0, stream>>>(
        xn16, wt + OFF_WQK, nullptr, nullptr, nullptr, qk16, v16, 512, 1024, sin_t, cos_t, rt, bucket);
    k_sort<<<BHD * NHASHK, 256, 0, stream>>>(bucket, st);
    k_attn<<<BHD * CHUNKS, 256, 0, stream>>>(qk16, v16, st, o4h, lg);
    k_combine<<<(BHD * TSEQ) / 4, 256, 0, stream>>>(o4h, lg, ctx16);
    k_gemm16<64, 64, 1><<<dim3(64, 8), 256, 0, stream>>>(
        ctx16, wt + OFF_WO, bo + L * DIMM, x1, nullptr, nullptr, nullptr, 512, 512, nullptr, nullptr, nullptr, nullptr);
    k_layernorm<<<NROWS, 256, 0, stream>>>(x1, ln2_s + L * DIMM, ln2_b + L * DIMM, xn16);
    k_gemm16<64, 128, 4><<<dim3(64, 16), 256, 0, stream>>>(
        xn16, wt + OFF_W1, b1 + L * FFD, nullptr, ffh16, nullptr, nullptr, 512, 2048, nullptr, nullptr, nullptr, nullptr);
    k_gemm16<64, 64, 1><<<dim3(64, 8), 256, 0, stream>>>(
        ffh16, wt + OFF_W2, b2 + L * DIMM, x2, nullptr, nullptr, nullptr, 2048, 512, nullptr, nullptr, nullptr, nullptr);
  }

  k_colmean1<<<512, 256, 0, stream>>>(x1, x2, part);
  k_colmean2<<<32, 256, 0, stream>>>(part, lnf_s, lnf_b, hm);
  k_head1<<<16, 256, 0, stream>>>(hm, Wf1, r1p);
  k_head2<<<2, 256, 0, stream>>>(r1p, bf1, Wout, bout, out);
}

// Round 13
// 500.975 us; speedup vs baseline: 1.1350x; 1.1350x over previous
//
#include <hip/hip_runtime.h>
#include <math.h>

#define TSEQ   2048
#define DIMM   512
#define NHEAD  8
#define DHD    64
#define BHD    16      // BATCH*HEADS
#define NHASHK 4
#define CHUNKS 128     // NHASHK * (TSEQ/64)
#define FFD    2048
#define NROWS  4096    // BATCH*TSEQ

#define OFF_WQK 0
#define OFF_WV  262144
#define OFF_WO  524288
#define OFF_W1  786432
#define OFF_W2  1835008
#define WT_TOT  2883584

typedef unsigned short u16;
typedef _Float16 f16;
typedef __attribute__((ext_vector_type(8))) _Float16 f16x8;
typedef __attribute__((ext_vector_type(4))) float f32x4;
typedef __attribute__((ext_vector_type(8))) unsigned short ushort8v;
typedef __attribute__((ext_vector_type(4))) unsigned short ushort4v;

__device__ inline u16 h16(float f) {
  union { f16 h; u16 u; } x;
  x.h = (f16)f;
  return x.u;
}
__device__ inline float f16f(u16 u) {
  union { u16 u; f16 h; } x;
  x.u = u;
  return (float)x.h;
}
__device__ inline f16x8 mk8f(unsigned a, unsigned b, unsigned c, unsigned d) {
  union { unsigned u[4]; f16x8 v; } x;
  x.u[0] = a; x.u[1] = b; x.u[2] = c; x.u[3] = d;
  return x.v;
}
__device__ inline float gelu_exact(float v) {
  return 0.5f * v * (1.0f + erff(v * 0.70710678118654752f));
}
// XOR swizzle for 128-byte LDS rows: 16B slot index ^= (row&7) -> 2-way max (free)
__device__ inline int swz128(int row, int colbyte) {
  return row * 128 + (colbyte ^ ((row & 7) << 4));
}
// transposed V LDS: byte address of Vt[d][k] (u16), stride 264B + half offset
#define VT(d, k) ((d) * 264 + (((d) & 32) ? 8 : 0) + ((k) << 1))

// ---------------- embed ----------------
__global__ __launch_bounds__(128) void k_embed(const int* __restrict__ x, const float* __restrict__ emb,
                                               float* __restrict__ x1, float* __restrict__ x2) {
  int row = blockIdx.x;
  int tok = x[row];
  float4 v = ((const float4*)(emb + (size_t)tok * DIMM))[threadIdx.x];
  ((float4*)(x1 + (size_t)row * DIMM))[threadIdx.x] = v;
  ((float4*)(x2 + (size_t)row * DIMM))[threadIdx.x] = v;
}

// ---------------- sin/cos tables ----------------
__global__ __launch_bounds__(256) void k_sincos(float* __restrict__ sin_t, float* __restrict__ cos_t) {
  int idx = blockIdx.x * 256 + threadIdx.x;   // TSEQ*32
  int t = idx >> 5, i = idx & 31;
  float inv = powf(10000.0f, -(float)(2 * i) / 64.0f);
  float ang = (float)t * inv;
  sin_t[idx] = sinf(ang);
  cos_t[idx] = cosf(ang);
}

// ---------------- layernorm (row = 512) -> fp16 ----------------
__global__ __launch_bounds__(256) void k_layernorm(const float* __restrict__ x, const float* __restrict__ g,
                                                   const float* __restrict__ b, u16* __restrict__ dst) {
  int row = blockIdx.x, tid = threadIdx.x;
  const float* xr = x + (size_t)row * DIMM;
  float v0 = xr[tid], v1 = xr[tid + 256];
  int lane = tid & 63, w = tid >> 6;
  __shared__ float red[8];
  float s = v0 + v1;
#pragma unroll
  for (int o = 32; o; o >>= 1) s += __shfl_xor(s, o);
  if (lane == 0) red[w] = s;
  __syncthreads();
  float mu = (red[0] + red[1] + red[2] + red[3]) * (1.0f / DIMM);
  float d0 = v0 - mu, d1 = v1 - mu;
  float q = d0 * d0 + d1 * d1;
#pragma unroll
  for (int o = 32; o; o >>= 1) q += __shfl_xor(q, o);
  if (lane == 0) red[4 + w] = q;
  __syncthreads();
  float var = (red[4] + red[5] + red[6] + red[7]) * (1.0f / DIMM);
  float rstd = 1.0f / sqrtf(var + 1e-5f);
  size_t base = (size_t)row * DIMM;
  dst[base + tid] = h16(d0 * rstd * g[tid] + b[tid]);
  dst[base + tid + 256] = h16(d1 * rstd * g[tid + 256] + b[tid + 256]);
}

// ---------------- ALL-layer weight prep: transpose + fp16 (4 x 2820 blocks) ----------------
__global__ __launch_bounds__(256) void k_prep(const float* __restrict__ Wqk, const float* __restrict__ Wv,
                                              const float* __restrict__ Wo, const float* __restrict__ W1,
                                              const float* __restrict__ W2, const float* __restrict__ rot,
                                              u16* __restrict__ wt16, u16* __restrict__ rt16) {
  __shared__ float tile[32][33];
  const int L = blockIdx.x / 2820;
  const int idx = blockIdx.x - L * 2820;
  Wqk += (size_t)L * 262144;
  Wv  += (size_t)L * 262144;
  Wo  += (size_t)L * 262144;
  W1  += (size_t)L * 1048576;
  W2  += (size_t)L * 1048576;
  rot += (size_t)L * 4096;
  u16* wt = wt16 + (size_t)L * WT_TOT;
  u16* rt = rt16 + (size_t)L * 4096;
  const float* src;
  u16* dh;
  int K, N, k0, n0;
  if (idx < 768) {
    int w = idx >> 8, r = idx & 255;
    K = 512; N = 512; k0 = (r >> 4) << 5; n0 = (r & 15) << 5;
    src = (w == 0) ? Wqk : (w == 1) ? Wv : Wo;
    dh = wt + (size_t)w * 262144;
  } else if (idx < 1792) {
    int r = idx - 768;
    K = 512; N = 2048; k0 = (r >> 6) << 5; n0 = (r & 63) << 5;
    src = W1; dh = wt + OFF_W1;
  } else if (idx < 2816) {
    int r = idx - 1792;
    K = 2048; N = 512; k0 = (r >> 4) << 5; n0 = (r & 15) << 5;
    src = W2; dh = wt + OFF_W2;
  } else {
    int r = idx - 2816;
    K = 64; N = 64; k0 = (r >> 1) << 5; n0 = (r & 1) << 5;
    src = rot; dh = rt;
  }
  const int t = threadIdx.x;
  const int r = t >> 3, c4 = (t & 7) << 2;
  float4 v = *(const float4*)&src[(size_t)(k0 + r) * N + n0 + c4];
  tile[r][c4] = v.x; tile[r][c4 + 1] = v.y; tile[r][c4 + 2] = v.z; tile[r][c4 + 3] = v.w;
  __syncthreads();
  u16 hs[4];
#pragma unroll
  for (int i = 0; i < 4; ++i) hs[i] = h16(tile[c4 + i][r]);
  size_t o = (size_t)(n0 + r) * K + k0 + c4;
  *(ushort4v*)&dh[o] = (ushort4v){hs[0], hs[1], hs[2], hs[3]};
}

// ---------------- fp16 MFMA GEMM: C = A[M][K] * B^T (Bt[N][K]), BK=64, depth-2 prefetch ----------------
// STORE: 1 = out += val + bias (residual fp32); 4 = gelu(val+bias) -> fp16
//        5 = fused QKV: gn<512 -> rotary -> qk16 + fused LSH bucket; gn>=512 -> v16
template <int BM, int STORE>
__global__ __launch_bounds__(256) void k_gemm16(
    const u16* __restrict__ A, const u16* __restrict__ Bt,
    const float* __restrict__ bias, float* __restrict__ out,
    u16* __restrict__ out16, u16* __restrict__ qk16, u16* __restrict__ v16,
    int K, int N,
    const float* __restrict__ sin_t, const float* __restrict__ cos_t,
    const u16* __restrict__ rt16, int* __restrict__ bucket) {
  constexpr int MF = BM / 32;    // m-frags per wave
  constexpr int ACH = BM / 32;   // A 16B-chunks per thread per K-step
  __shared__ __align__(16) char AsB[BM * 128];
  __shared__ __align__(16) char BsB[64 * 128];
  const int bm = blockIdx.x * BM, bn = blockIdx.y << 6;
  const int tid = threadIdx.x, lane = tid & 63, wid = tid >> 6;
  const int wm = (wid >> 1) * (BM / 2), wn = (wid & 1) << 5;
  const int l16 = lane & 15, g = lane >> 4;
  f32x4 acc[MF][2];
#pragma unroll
  for (int m = 0; m < MF; ++m) { acc[m][0] = (f32x4){0,0,0,0}; acc[m][1] = (f32x4){0,0,0,0}; }

  const int srow = tid >> 3;            // 0..31
  const int scolb = (tid & 7) << 4;     // 16B chunk col within 128B row
  const u16* ap = A + (size_t)(bm + srow) * K + ((tid & 7) << 3);
  const u16* bp = Bt + (size_t)(bn + srow) * K + ((tid & 7) << 3);

  // two named in-flight register sets (depth-2 pipeline; no runtime indexing)
  ushort8v paA[ACH], pbA[2], paB[ACH], pbB[2];
#pragma unroll
  for (int i = 0; i < ACH; ++i) paA[i] = *(const ushort8v*)(ap + (size_t)(i << 5) * K);
#pragma unroll
  for (int i = 0; i < 2; ++i) pbA[i] = *(const ushort8v*)(bp + (size_t)(i << 5) * K);
#pragma unroll
  for (int i = 0; i < ACH; ++i) paB[i] = *(const ushort8v*)(ap + (size_t)(i << 5) * K + 64);
#pragma unroll
  for (int i = 0; i < 2; ++i) pbB[i] = *(const ushort8v*)(bp + (size_t)(i << 5) * K + 64);

  auto gstep = [&](ushort8v (&PA)[ACH], ushort8v (&PB)[2], int S) {
#pragma unroll
    for (int i = 0; i < ACH; ++i)
      *(ushort8v*)(AsB + swz128(srow + (i << 5), scolb)) = PA[i];
#pragma unroll
    for (int i = 0; i < 2; ++i)
      *(ushort8v*)(BsB + swz128(srow + (i << 5), scolb)) = PB[i];
    __syncthreads();
    const int kf = (S + 2) << 6;
    if (kf < K) {   // issue loads for step S+2 (in flight across ~2 K-steps)
#pragma unroll
      for (int i = 0; i < ACH; ++i) PA[i] = *(const ushort8v*)(ap + (size_t)(i << 5) * K + kf);
#pragma unroll
      for (int i = 0; i < 2; ++i) PB[i] = *(const ushort8v*)(bp + (size_t)(i << 5) * K + kf);
    }
    f16x8 af[MF][2], bfr[2][2];
#pragma unroll
    for (int m = 0; m < MF; ++m)
#pragma unroll
      for (int ks = 0; ks < 2; ++ks)
        af[m][ks] = *(const f16x8*)(AsB + swz128(wm + (m << 4) + l16, ((ks << 2) + g) << 4));
#pragma unroll
    for (int n = 0; n < 2; ++n)
#pragma unroll
      for (int ks = 0; ks < 2; ++ks)
        bfr[n][ks] = *(const f16x8*)(BsB + swz128(wn + (n << 4) + l16, ((ks << 2) + g) << 4));
#pragma unroll
    for (int m = 0; m < MF; ++m)
#pragma unroll
      for (int n = 0; n < 2; ++n)
#pragma unroll
        for (int ks = 0; ks < 2; ++ks)
          acc[m][n] = __builtin_amdgcn_mfma_f32_16x16x32_f16(af[m][ks], bfr[n][ks], acc[m][n], 0, 0, 0);
    __syncthreads();
  };

  const int nsteps = K >> 6;            // always even (K = 512 or 2048)
  for (int s = 0; s < nsteps; s += 2) {
    gstep(paA, pbA, s);
    gstep(paB, pbB, s + 1);
  }

  // bucket path: preload rot^T (8KB) into regs early to hide latency
  const bool do_bucket = (STORE == 5) && (bn < 512);
  ushort8v prt0{}, prt1{};
  if (do_bucket) {
    int i0 = tid, i1 = tid + 256;               // 16B chunk ids, 512 total
    prt0 = *(const ushort8v*)(rt16 + (i0 >> 3) * 64 + ((i0 & 7) << 3));
    prt1 = *(const ushort8v*)(rt16 + (i1 >> 3) * 64 + ((i1 & 7) << 3));
  }

  // epilogue (C/D: col = lane&15 -> B rows, row = (lane>>4)*4 + reg -> A rows)
#pragma unroll
  for (int m = 0; m < MF; ++m) {
#pragma unroll
    for (int n = 0; n < 2; ++n) {
      const int gn = bn + wn + (n << 4) + l16;
      float bv = 0.f;
      if (STORE == 1 || STORE == 4) bv = bias[gn];
#pragma unroll
      for (int r = 0; r < 4; ++r) {
        const int gm = bm + wm + (m << 4) + (g << 2) + r;
        float val = acc[m][n][r];
        if (STORE == 1) {
          out[(size_t)gm * N + gn] += val + bv;
        } else if (STORE == 4) {
          out16[(size_t)gm * N + gn] = h16(gelu_exact(val + bv));
        } else {  // STORE == 5
          const float pv = __shfl_xor(val, 1);
          const int bb = gm >> 11, tt = gm & (TSEQ - 1);
          if (gn < 512) {
            const int hh = gn >> 6, dd = gn & 63;
            const int ip = dd >> 1;
            float cz = cos_t[tt * 32 + ip], sz = sin_t[tt * 32 + ip];
            float o = (dd & 1) ? (val * cz + pv * sz) : (val * cz - pv * sz);
            u16 oh = h16(o);
            qk16[((size_t)((bb * NHEAD + hh) * TSEQ + tt)) * DHD + dd] = oh;
            // stage rotated qk row into AsB for the fused bucket GEMM
            *(u16*)(AsB + swz128(gm - bm, dd << 1)) = oh;
          } else {
            const int gnn = gn - 512;
            const int hh = gnn >> 6, dd = gnn & 63;
            v16[((size_t)((bb * NHEAD + hh) * TSEQ + tt)) * DHD + dd] = h16(val);
          }
        }
      }
    }
  }

  if (do_bucket) {
    // write rot^T into BsB (swizzled), then mini-GEMM 64x64 @ 64x64 + argmax
    {
      int i0 = tid, i1 = tid + 256;
      *(ushort8v*)(BsB + swz128(i0 >> 3, (i0 & 7) << 4)) = prt0;
      *(ushort8v*)(BsB + swz128(i1 >> 3, (i1 & 7) << 4)) = prt1;
    }
    __syncthreads();
    const int bwm = (wid >> 1) << 5;    // token rows 0/32
    const int bwn = (wid & 1) << 5;     // hash cols 0/32
    f32x4 bacc[2][2];
#pragma unroll
    for (int m = 0; m < 2; ++m) { bacc[m][0] = (f32x4){0,0,0,0}; bacc[m][1] = (f32x4){0,0,0,0}; }
#pragma unroll
    for (int ks = 0; ks < 2; ++ks) {
      f16x8 bfr[2];
#pragma unroll
      for (int n = 0; n < 2; ++n)
        bfr[n] = *(const f16x8*)(BsB + swz128(bwn + (n << 4) + l16, (ks << 6) + (g << 4)));
#pragma unroll
      for (int m = 0; m < 2; ++m) {
        f16x8 afr = *(const f16x8*)(AsB + swz128(bwm + (m << 4) + l16, (ks << 6) + (g << 4)));
#pragma unroll
        for (int n = 0; n < 2; ++n)
          bacc[m][n] = __builtin_amdgcn_mfma_f32_16x16x32_f16(afr, bfr[n], bacc[m][n], 0, 0, 0);
      }
    }
    const int bb = bm >> 11;
    const int hh = bn >> 6;
#pragma unroll
    for (int m = 0; m < 2; ++m)
#pragma unroll
      for (int n = 0; n < 2; ++n) {
        const int hcol = (bwn >> 4) + n;
#pragma unroll
        for (int r = 0; r < 4; ++r) {
          float v = bacc[m][n][r];
          float best = v; int bi = l16;
          if (-v > best) { best = -v; bi = 16 + l16; }
#pragma unroll
          for (int o = 1; o < 16; o <<= 1) {
            float ob = __shfl_xor(best, o);
            int obi = __shfl_xor(bi, o);
            if (ob > best || (ob == best && obi < bi)) { best = ob; bi = obi; }
          }
          if (l16 == 0) {
            int t = (bm & (TSEQ - 1)) + bwm + (m << 4) + (g << 2) + r;
            bucket[((size_t)((bb * NHEAD + hh) * NHASHK) + hcol) * TSEQ + t] = bi;
          }
        }
      }
  }
}

// ---------------- stable counting sort per (bh,h): 32 buckets, 2048 items ----------------
__global__ __launch_bounds__(256) void k_sort(const int* __restrict__ bucket, int* __restrict__ st) {
  __shared__ int hist[256][33];
  __shared__ int chunk[8][32];
  __shared__ int bbase[32];
  const int seg = blockIdx.x;
  const int tid = threadIdx.x;
  const int* bk = bucket + (size_t)seg * TSEQ;
  int4 u0 = *(const int4*)(bk + tid * 8);
  int4 u1 = *(const int4*)(bk + tid * 8 + 4);
  int myb[8] = {u0.x, u0.y, u0.z, u0.w, u1.x, u1.y, u1.z, u1.w};
#pragma unroll
  for (int j = 0; j < 33; ++j) hist[tid][j] = 0;
  __syncthreads();
#pragma unroll
  for (int i = 0; i < 8; ++i) hist[tid][myb[i]]++;
  __syncthreads();
  // two-level exclusive scan over producers (256) per bucket (32)
  const int b = tid & 31, c = tid >> 5;
  int ssum = 0;
  for (int g2 = c * 32; g2 < c * 32 + 32; ++g2) ssum += hist[g2][b];
  chunk[c][b] = ssum;
  __syncthreads();
  if (tid < 32) {
    int run = 0;
    for (int cc = 0; cc < 8; ++cc) { int v = chunk[cc][tid]; chunk[cc][tid] = run; run += v; }
    bbase[tid] = run;
  }
  __syncthreads();
  if (tid == 0) {
    int s = 0;
    for (int j = 0; j < 32; ++j) { int v = bbase[j]; bbase[j] = s; s += v; }
  }
  __syncthreads();
  int run = chunk[c][b];
  for (int g2 = c * 32; g2 < c * 32 + 32; ++g2) { int v = hist[g2][b]; hist[g2][b] = run; run += v; }
  __syncthreads();
  int* dst = st + (size_t)seg * TSEQ;
#pragma unroll
  for (int i = 0; i < 8; ++i) {
    int bb2 = myb[i];
    int p = bbase[bb2] + hist[tid][bb2];
    hist[tid][bb2]++;
    dst[p] = tid * 8 + i;
  }
}

// ---------------- chunked LSH attention (fp16 MFMA, K + transposed-V in LDS) ----------------
__global__ __launch_bounds__(256) void k_attn(const u16* __restrict__ qk16,
                                              const u16* __restrict__ v16,
                                              const int* __restrict__ st,
                                              u16* __restrict__ o4h, float* __restrict__ lg) {
  __shared__ __align__(16) char Kb[128 * 128];        // swizzled fp16 K rows
  __shared__ __align__(16) char Vb[64 * 264 + 16];    // transposed V: Vt[d][k]
  __shared__ float inv_norm[128];
  __shared__ int tids[128];
  __shared__ float pn[256];
  const int blk = blockIdx.x;
  const int c = blk & (CHUNKS - 1), bh = blk >> 7;
  const int h = c >> 5;
  const int tid = threadIdx.x, lane = tid & 63, wid = tid >> 6;
  const int l16 = lane & 15, g = lane >> 4;

  if (tid < 128) {
    int cc = (tid < 64) ? c : ((c + CHUNKS - 1) & (CHUNKS - 1));
    tids[tid] = st[bh * (NHASHK * TSEQ) + cc * 64 + (tid & 63)];
  }
  __syncthreads();
  {
    const int r = tid >> 1, hf = tid & 1;
    const u16* qsrc = qk16 + ((size_t)bh * TSEQ + tids[r]) * 64 + hf * 32;
    const u16* vsrc = v16 + ((size_t)bh * TSEQ + tids[r]) * 64 + hf * 32;
    float ss = 0.f;
#pragma unroll
    for (int i = 0; i < 4; ++i) {
      ushort8v u = *(const ushort8v*)(qsrc + i * 8);
      *(ushort8v*)(Kb + swz128(r, hf * 64 + i * 16)) = u;
#pragma unroll
      for (int j = 0; j < 8; ++j) { float f = f16f(u[j]); ss += f * f; }
      ushort8v vv8 = *(const ushort8v*)(vsrc + i * 8);
#pragma unroll
      for (int j = 0; j < 8; ++j)
        *(u16*)(Vb + VT(hf * 32 + i * 8 + j, r)) = vv8[j];
    }
    pn[tid] = ss;
  }
  __syncthreads();
  if (tid < 128) {
    float s2 = pn[2 * tid] + pn[2 * tid + 1];
    inv_norm[tid] = 1.0f / fmaxf(sqrtf(s2), 1e-12f);
  }
  __syncthreads();

  const int qrow = (wid << 4) + l16;
  const int tq = tids[qrow];
  const size_t obase = (size_t)(bh * NHASHK + h) * TSEQ + tq;

  // S^T = K_raw · Q^T : lane holds S[k][q] for its q-column
  f32x4 accs[8];
#pragma unroll
  for (int i = 0; i < 8; ++i) accs[i] = (f32x4){0, 0, 0, 0};
#pragma unroll
  for (int s = 0; s < 2; ++s) {
    f16x8 qf = *(const f16x8*)(Kb + swz128(qrow, ((s << 2) + g) << 4));
#pragma unroll
    for (int mf = 0; mf < 8; ++mf) {
      f16x8 afr = *(const f16x8*)(Kb + swz128(mf * 16 + l16, ((s << 2) + g) << 4));
      accs[mf] = __builtin_amdgcn_mfma_f32_16x16x32_f16(afr, qf, accs[mf], 0, 0, 0);
    }
  }
  float pv[8][4];
  float mx = -3e38f;
#pragma unroll
  for (int mf = 0; mf < 8; ++mf) {
    float4 invn = *(const float4*)&inv_norm[mf * 16 + g * 4];
    int4 tk = *(const int4*)&tids[mf * 16 + g * 4];
    float inva[4] = {invn.x, invn.y, invn.z, invn.w};
    int tka[4] = {tk.x, tk.y, tk.z, tk.w};
#pragma unroll
    for (int r = 0; r < 4; ++r) {
      float d = accs[mf][r] * inva[r] * 0.125f;
      if (tka[r] == tq) d = -5e4f;
      pv[mf][r] = d;
      mx = fmaxf(mx, d);
    }
  }
  mx = fmaxf(mx, __shfl_xor(mx, 16));
  mx = fmaxf(mx, __shfl_xor(mx, 32));
  float sum = 0.f;
#pragma unroll
  for (int mf = 0; mf < 8; ++mf)
#pragma unroll
    for (int r = 0; r < 4; ++r) {
      float e = __expf(pv[mf][r] - mx);
      pv[mf][r] = e;
      sum += e;
    }
  sum += __shfl_xor(sum, 16);
  sum += __shfl_xor(sum, 32);
  float lse = __logf(sum) + mx;
  float rs = 1.0f / sum;
  if (g == 0) lg[obase] = lse;
  // pack P pairs fp16: P2[mf][m] = (p_{2m}, p_{2m+1}) for k = 16mf + 4g + {2m,2m+1}
  unsigned P2[8][2];
#pragma unroll
  for (int mf = 0; mf < 8; ++mf)
#pragma unroll
    for (int m = 0; m < 2; ++m) {
      float p0 = pv[mf][2 * m] * rs, p1 = pv[mf][2 * m + 1] * rs;
      P2[mf][m] = (unsigned)h16(p0) | ((unsigned)h16(p1) << 16);
    }
  // PV: O^T = V^T · P^T  (A = V^T from transposed LDS, B = P via shfl redistribution)
  f32x4 acco[4];
#pragma unroll
  for (int i = 0; i < 4; ++i) acco[i] = (f32x4){0, 0, 0, 0};
#pragma unroll
  for (int s = 0; s < 4; ++s) {
    unsigned bw[4];
#pragma unroll
    for (int w = 0; w < 4; ++w) {
      int srl = l16 + (((2 * g + (w >> 1)) & 3) << 4);
      unsigned a0 = __shfl(P2[2 * s][w & 1], srl);
      unsigned a1 = __shfl(P2[2 * s + 1][w & 1], srl);
      bw[w] = (g >> 1) ? a1 : a0;
    }
    f16x8 pb = mk8f(bw[0], bw[1], bw[2], bw[3]);
    const int k0 = s * 32 + g * 8;
#pragma unroll
    for (int mf = 0; mf < 4; ++mf) {
      const int dcol = mf * 16 + l16;
      uint2 v0 = *(const uint2*)(Vb + VT(dcol, k0));
      uint2 v1 = *(const uint2*)(Vb + VT(dcol, k0 + 4));
      f16x8 vf = mk8f(v0.x, v0.y, v1.x, v1.y);
      acco[mf] = __builtin_amdgcn_mfma_f32_16x16x32_f16(vf, pb, acco[mf], 0, 0, 0);
    }
  }
#pragma unroll
  for (int mf = 0; mf < 4; ++mf) {
    ushort4v o4s = {h16(acco[mf][0]), h16(acco[mf][1]), h16(acco[mf][2]), h16(acco[mf][3])};
    *(ushort4v*)&o4h[obase * 64 + mf * 16 + g * 4] = o4s;
  }
}

// ---------------- combine hash rounds -> ctx fp16 [B,T,512] ----------------
__global__ __launch_bounds__(256) void k_combine(const u16* __restrict__ o4h, const float* __restrict__ lg,
                                                 u16* __restrict__ ctx16) {
  int tok = blockIdx.x * 4 + (threadIdx.x >> 6);   // over BHD*TSEQ
  int dd = threadIdx.x & 63;
  int bh = tok >> 11, t = tok & (TSEQ - 1);
  size_t base = (size_t)bh * NHASHK * TSEQ + t;
  float l0 = lg[base], l1 = lg[base + TSEQ], l2 = lg[base + 2 * TSEQ], l3 = lg[base + 3 * TSEQ];
  float m = fmaxf(fmaxf(l0, l1), fmaxf(l2, l3));
  float e0 = expf(l0 - m), e1 = expf(l1 - m), e2 = expf(l2 - m), e3 = expf(l3 - m);
  float inv = 1.0f / (e0 + e1 + e2 + e3);
  float o = (e0 * f16f(o4h[base * 64 + dd]) + e1 * f16f(o4h[(base + TSEQ) * 64 + dd]) +
             e2 * f16f(o4h[(base + 2 * TSEQ) * 64 + dd]) + e3 * f16f(o4h[(base + 3 * TSEQ) * 64 + dd])) * inv;
  int b = bh >> 3, hh = bh & 7;
  ctx16[((size_t)(b * TSEQ + t)) * DIMM + hh * DHD + dd] = h16(o);
}

// ---------------- fused final-LN + column-mean stage 1: 512 blocks x 8 rows ----------------
__global__ __launch_bounds__(256) void k_colmean1(const float* __restrict__ x1, const float* __restrict__ x2,
                                                  float* __restrict__ part) {
  const int blk = blockIdx.x;            // bb*256 + ch
  const int bb = blk >> 8, ch = blk & 255;
  const int tid = threadIdx.x, lane = tid & 63, w = tid >> 6;
  __shared__ float red[8];
  float a0 = 0.f, a1 = 0.f;
  for (int i = 0; i < 8; ++i) {
    int row = bb * TSEQ + ch * 8 + i;
    size_t base = (size_t)row * DIMM;
    float v0 = 0.5f * (x1[base + tid] + x2[base + tid]);
    float v1 = 0.5f * (x1[base + tid + 256] + x2[base + tid + 256]);
    float s = v0 + v1;
#pragma unroll
    for (int o = 32; o; o >>= 1) s += __shfl_xor(s, o);
    if (lane == 0) red[w] = s;
    __syncthreads();
    float mu = (red[0] + red[1] + red[2] + red[3]) * (1.0f / DIMM);
    float d0 = v0 - mu, d1 = v1 - mu;
    float q = d0 * d0 + d1 * d1;
#pragma unroll
    for (int o = 32; o; o >>= 1) q += __shfl_xor(q, o);
    if (lane == 0) red[4 + w] = q;
    __syncthreads();
    float var = (red[4] + red[5] + red[6] + red[7]) * (1.0f / DIMM);
    float rstd = 1.0f / sqrtf(var + 1e-5f);
    a0 += d0 * rstd;
    a1 += d1 * rstd;
    __syncthreads();
  }
  part[(size_t)blk * DIMM + tid] = a0;
  part[(size_t)blk * DIMM + tid + 256] = a1;
}

__global__ __launch_bounds__(256) void k_colmean2(const float* __restrict__ part,
                                                  const float* __restrict__ g, const float* __restrict__ b,
                                                  float* __restrict__ hm) {
  int gidx = blockIdx.x * 256 + threadIdx.x;   // 8192 = 1024 outputs x 8
  int oid = gidx >> 3, sub = gidx & 7;
  int bb = oid >> 9, d = oid & 511;
  float s = 0.f;
  for (int c = sub; c < 256; c += 8) s += part[((size_t)(bb * 256 + c)) * DIMM + d];
  s += __shfl_xor(s, 1);
  s += __shfl_xor(s, 2);
  s += __shfl_xor(s, 4);
  if (sub == 0) hm[oid] = s * (1.0f / TSEQ) * g[d] + b[d];
}

// ---------------- head (split-K head1 + reducing head2) ----------------
__global__ __launch_bounds__(256) void k_head1(const float* __restrict__ hm, const float* __restrict__ Wf1,
                                               float* __restrict__ r1p) {
  int b = blockIdx.x & 1, kc = blockIdx.x >> 1;   // 16 blocks: 2 batch x 8 k-chunks
  int j = threadIdx.x;
  float acc = 0;
  for (int k = kc * 64; k < kc * 64 + 64; ++k) acc += hm[b * DIMM + k] * Wf1[k * 256 + j];
  r1p[(size_t)(kc * 2 + b) * 256 + j] = acc;
}

__global__ __launch_bounds__(256) void k_head2(const float* __restrict__ r1p, const float* __restrict__ bf1,
                                               const float* __restrict__ Wout, const float* __restrict__ bout,
                                               float* __restrict__ outp) {
  int b = blockIdx.x;
  int tid = threadIdx.x, lane = tid & 63, w = tid >> 6;
  float s = 0.f;
#pragma unroll
  for (int kc = 0; kc < 8; ++kc) s += r1p[(size_t)(kc * 2 + b) * 256 + tid];
  float v = fmaxf(s + bf1[tid], 0.0f) * Wout[tid];
#pragma unroll
  for (int o = 32; o; o >>= 1) v += __shfl_xor(v, o);
  __shared__ float red[4];
  if (lane == 0) red[w] = v;
  __syncthreads();
  if (tid == 0) outp[b] = red[0] + red[1] + red[2] + red[3] + bout[0];
}

extern "C" void kernel_launch(void* const* d_in, const int* in_sizes, int n_in,
                              void* d_out, int out_size, void* d_ws, size_t ws_size,
                              hipStream_t stream) {
  const int*   x         = (const int*)d_in[0];
  const float* token_emb = (const float*)d_in[1];
  const float* ln1_s     = (const float*)d_in[2];
  const float* ln1_b     = (const float*)d_in[3];
  const float* Wqk       = (const float*)d_in[4];
  const float* Wv        = (const float*)d_in[5];
  const float* Wo        = (const float*)d_in[6];
  const float* bo        = (const float*)d_in[7];
  const float* ln2_s     = (const float*)d_in[8];
  const float* ln2_b     = (const float*)d_in[9];
  const float* W1        = (const float*)d_in[10];
  const float* b1        = (const float*)d_in[11];
  const float* W2        = (const float*)d_in[12];
  const float* b2        = (const float*)d_in[13];
  const float* rotations = (const float*)d_in[14];
  const float* lnf_s     = (const float*)d_in[15];
  const float* lnf_b     = (const float*)d_in[16];
  const float* Wf1       = (const float*)d_in[17];
  const float* bf1       = (const float*)d_in[18];
  const float* Wout      = (const float*)d_in[19];
  const float* bout      = (const float*)d_in[20];
  float* out = (float*)d_out;

  char* ws = (char*)d_ws;
  size_t off = 0;
  auto alloc = [&](size_t nbytes) {
    char* p = ws + off;
    off += (nbytes + 255) & ~(size_t)255;
    return p;
  };
  float*  x1     = (float*)alloc((size_t)NROWS * DIMM * 4);
  float*  x2     = (float*)alloc((size_t)NROWS * DIMM * 4);
  u16*    xn16   = (u16*)alloc((size_t)NROWS * DIMM * 2);
  u16*    qk16   = (u16*)alloc((size_t)BHD * TSEQ * DHD * 2);
  u16*    v16    = (u16*)alloc((size_t)BHD * TSEQ * DHD * 2);
  u16*    ffh16  = (u16*)alloc((size_t)NROWS * FFD * 2);
  u16*    o4h    = (u16*)alloc((size_t)BHD * NHASHK * TSEQ * DHD * 2);
  float*  lg     = (float*)alloc((size_t)BHD * NHASHK * TSEQ * 4);
  float*  sin_t  = (float*)alloc((size_t)TSEQ * 32 * 4);
  float*  cos_t  = (float*)alloc((size_t)TSEQ * 32 * 4);
  float*  part   = (float*)alloc((size_t)512 * DIMM * 4);
  float*  hm     = (float*)alloc(2 * DIMM * 4);
  float*  r1p    = (float*)alloc(16 * 256 * 4);
  int*    bucket = (int*)alloc((size_t)BHD * NHASHK * TSEQ * 4);
  int*    st     = (int*)alloc((size_t)BHD * NHASHK * TSEQ * 4);
  u16*    wt16   = (u16*)alloc((size_t)4 * WT_TOT * 2);
  u16*    rott16 = (u16*)alloc((size_t)4 * 64 * 64 * 2);
  u16*    ctx16  = xn16;   // alias: lifetimes disjoint

  k_embed<<<NROWS, 128, 0, stream>>>(x, token_emb, x1, x2);
  k_sincos<<<(TSEQ * 32) / 256, 256, 0, stream>>>(sin_t, cos_t);
  k_prep<<<4 * 2820, 256, 0, stream>>>(Wqk, Wv, Wo, W1, W2, rotations, wt16, rott16);

  for (int L = 0; L < 4; ++L) {
    u16* wt = wt16 + (size_t)L * WT_TOT;
    u16* rt = rott16 + (size_t)L * 4096;

    k_layernorm<<<NROWS, 256, 0, stream>>>(x2, ln1_s + L * DIMM, ln1_b + L * DIMM, xn16);
    // fused QK+V GEMM (+LSH bucket in qk-half epilogues): B = [Wqk^T ; Wv^T]
    k_gemm16<64, 5><<<dim3(64, 16), 256, 0, stream>>>(
        xn16, wt + OFF_WQK, nullptr, nullptr, nullptr, qk16, v16, 512, 1024, sin_t, cos_t, rt, bucket);
    k_sort<<<BHD * NHASHK, 256, 0, stream>>>(bucket, st);
    k_attn<<<BHD * CHUNKS, 256, 0, stream>>>(qk16, v16, st, o4h, lg);
    k_combine<<<(BHD * TSEQ) / 4, 256, 0, stream>>>(o4h, lg, ctx16);
    k_gemm16<64, 1><<<dim3(64, 8), 256, 0, stream>>>(
        ctx16, wt + OFF_WO, bo + L * DIMM, x1, nullptr, nullptr, nullptr, 512, 512, nullptr, nullptr, nullptr, nullptr);
    k_layernorm<<<NROWS, 256, 0, stream>>>(x1, ln2_s + L * DIMM, ln2_b + L * DIMM, xn16);
    k_gemm16<64, 4><<<dim3(64, 32), 256, 0, stream>>>(
        xn16, wt + OFF_W1, b1 + L * FFD, nullptr, ffh16, nullptr, nullptr, 512, 2048, nullptr, nullptr, nullptr, nullptr);
    k_gemm16<64, 1><<<dim3(64, 8), 256, 0, stream>>>(
        ffh16, wt + OFF_W2, b2 + L * DIMM, x2, nullptr, nullptr, nullptr, 2048, 512, nullptr, nullptr, nullptr, nullptr);
  }

  k_colmean1<<<512, 256, 0, stream>>>(x1, x2, part);
  k_colmean2<<<32, 256, 0, stream>>>(part, lnf_s, lnf_b, hm);
  k_head1<<<16, 256, 0, stream>>>(hm, Wf1, r1p);
  k_head2<<<2, 256, 0, stream>>>(r1p, bf1, Wout, bout, out);
}